// Round 14
// baseline (210.273 us; speedup 1.0000x reference)
//
#include <hip/hip_runtime.h>
#include <hip/hip_bf16.h>

// Problem: B=2, T=2048, C=1024, H=16, D=64 causal self-attention fwd.
// All inputs fp32; output fp32. Compute in bf16 MFMA (threshold = 2% of max|ref|).

namespace {

constexpr int TT = 2048;
constexpr int CC = 1024;
constexpr int HH = 16;
constexpr int DD = 64;

using bf16x8 = __attribute__((ext_vector_type(8))) __bf16;
using bf16x4 = __attribute__((ext_vector_type(4))) __bf16;
using f32x4  = __attribute__((ext_vector_type(4))) float;
using us8    = __attribute__((ext_vector_type(8))) unsigned short;

__device__ __forceinline__ unsigned short f2b(float f) {
  unsigned u = __float_as_uint(f);
  u += 0x7fffu + ((u >> 16) & 1u);   // RNE
  return (unsigned short)(u >> 16);
}

// async global->LDS, 16B per lane; LDS dest is wave-uniform base + lane*16
__device__ __forceinline__ void gload16(const void* g, void* l) {
  __builtin_amdgcn_global_load_lds(
      (const __attribute__((address_space(1))) void*)g,
      (__attribute__((address_space(3))) void*)l, 16, 0, 0);
}

#if __has_builtin(__builtin_amdgcn_exp2f)
#define FEXP2 __builtin_amdgcn_exp2f
#else
#define FEXP2 exp2f
#endif

// 1/sqrt(64) * log2(e): folded into the Q projection epilogue -> attn softmax
// runs directly in the exp2 domain with NO per-score scaling.
#define SCALE2 0.18033688011112042f

} // namespace

// ---------------- fp32 -> bf16 conversion: all 5 tensors in ONE launch ----------------
__global__ void k_cvt_all(const float* __restrict__ x,
                          const float* __restrict__ wq, const float* __restrict__ wk,
                          const float* __restrict__ wv, const float* __restrict__ wo,
                          unsigned short* __restrict__ dst) {
  const int i = blockIdx.x * 256 + threadIdx.x;   // 0 .. 2097151 float4s
  const float* src; int off;
  if (i < 1048576)      { src = x;  off = i; }
  else if (i < 1310720) { src = wq; off = i - 1048576; }
  else if (i < 1572864) { src = wk; off = i - 1310720; }
  else if (i < 1835008) { src = wv; off = i - 1572864; }
  else                  { src = wo; off = i - 1835008; }
  float4 v = reinterpret_cast<const float4*>(src)[off];
  ushort4 o;
  o.x = f2b(v.x); o.y = f2b(v.y); o.z = f2b(v.z); o.w = f2b(v.w);
  reinterpret_cast<ushort4*>(dst)[i] = o;
}

// ---------------- fused QKV GEMM, 2-deep counted-vmcnt pipeline (R10 verified) ----------------
// Q output is PRE-SCALED by SCALE2 (softmax exp2-domain fold).
__global__ __launch_bounds__(256, 3) void k_gemm_qkv(
    const unsigned short* __restrict__ A,    // x bf16 [4096][1024]
    const unsigned short* __restrict__ Wq,
    const unsigned short* __restrict__ Wk,
    const unsigned short* __restrict__ Wv,
    const float* __restrict__ bq,
    const float* __restrict__ bk,
    const float* __restrict__ bv,
    unsigned short* __restrict__ qd,         // [BH][T][D]  (pre-scaled)
    unsigned short* __restrict__ kd,         // [BH][T][D]
    unsigned short* __restrict__ vd)         // [BH][D][T]
{
  __shared__ unsigned short la[2][128 * 32];   // 2 x 8 KB
  __shared__ unsigned short lb[2][128 * 32];
  const int tid = threadIdx.x;
  const int lane = tid & 63;
  const int wid = tid >> 6;
  const int l15 = lane & 15, lg = lane >> 4;
  const int wm = (wid & 1) * 64, wn = (wid >> 1) * 64;
  const int bm = blockIdx.x;
  const int wsel = blockIdx.y >> 3;          // 0=Q 1=K 2=V
  const int bnl = blockIdx.y & 7;

  const unsigned short* W = (wsel == 0) ? Wq : (wsel == 1) ? Wk : Wv;
  const float* bias = (wsel == 0) ? bq : (wsel == 1) ? bk : bv;

  const int srow = lane >> 2;                // 0..15 within segment
  const int sko  = (lane & 3) * 8;           // k-chunk 0/8/16/24

  auto STAGE = [&](int buf, int kt) {        // 4 gloads per wave
#pragma unroll
    for (int s = 0; s < 2; ++s) {
      const int seg = wid * 2 + s;           // 0..7 (16 rows each)
      const int row = seg * 16 + srow;
      gload16(&A[(bm * 128 + row) * CC + kt * 32 + sko], &la[buf][seg * 512]);
      gload16(&W[(bnl * 128 + row) * CC + kt * 32 + sko], &lb[buf][seg * 512]);
    }
  };

  f32x4 acc[4][4];
#pragma unroll
  for (int i = 0; i < 4; ++i)
#pragma unroll
    for (int j = 0; j < 4; ++j) acc[i][j] = f32x4{0.f, 0.f, 0.f, 0.f};

  auto COMPUTE = [&](int buf) {
    bf16x8 af[4], bf[4];
#pragma unroll
    for (int mi = 0; mi < 4; ++mi)
      af[mi] = __builtin_bit_cast(bf16x8,
        *reinterpret_cast<const us8*>(&la[buf][(wm + mi * 16 + l15) * 32 + lg * 8]));
#pragma unroll
    for (int ni = 0; ni < 4; ++ni)
      bf[ni] = __builtin_bit_cast(bf16x8,
        *reinterpret_cast<const us8*>(&lb[buf][(wn + ni * 16 + l15) * 32 + lg * 8]));
#pragma unroll
    for (int mi = 0; mi < 4; ++mi)
#pragma unroll
      for (int ni = 0; ni < 4; ++ni)
        acc[mi][ni] = __builtin_amdgcn_mfma_f32_16x16x32_bf16(af[mi], bf[ni], acc[mi][ni], 0, 0, 0);
  };

  STAGE(0, 0);
  STAGE(1, 1);
  int cur = 0;
  for (int kt = 0; kt < CC / 32 - 1; ++kt) {
    asm volatile("s_waitcnt vmcnt(4)" ::: "memory");   // tile kt landed; kt+1 flying
    __builtin_amdgcn_s_barrier();
    COMPUTE(cur);
    __builtin_amdgcn_s_barrier();
    if (kt < CC / 32 - 2) STAGE(cur, kt + 2);
    cur ^= 1;
  }
  asm volatile("s_waitcnt vmcnt(0)" ::: "memory");      // peeled last step: full drain
  __builtin_amdgcn_s_barrier();
  COMPUTE(cur);

  // epilogue: C/D col = lane&15, row = (lane>>4)*4 + r
#pragma unroll
  for (int ni = 0; ni < 4; ++ni) {
    const int nl = bnl * 128 + wn + ni * 16 + l15;   // 0..1023
    const float bvl = bias[nl];
    const int hh = nl >> 6, d = nl & (DD - 1);
#pragma unroll
    for (int mi = 0; mi < 4; ++mi) {
#pragma unroll
      for (int r = 0; r < 4; ++r) {
        const int m = bm * 128 + wm + mi * 16 + lg * 4 + r;
        float val = acc[mi][ni][r] + bvl;
        if (wsel == 0) val *= SCALE2;                  // pre-scale Q
        const unsigned short bb = f2b(val);
        const int b = m >> 11, t = m & (TT - 1);
        if (wsel == 0)
          qd[((b * HH + hh) * TT + t) * DD + d] = bb;
        else if (wsel == 1)
          kd[((b * HH + hh) * TT + t) * DD + d] = bb;
        else
          vd[((b * HH + hh) * DD + d) * TT + t] = bb;
      }
    }
  }
}

// ---------------- output projection GEMM, 2-deep counted-vmcnt (R10 verified) ----------------
__global__ __launch_bounds__(256, 2) void k_gemm_o(
    const unsigned short* __restrict__ A,    // y bf16 [4096][1024]
    const unsigned short* __restrict__ W,    // Wo bf16 [1024][1024]
    const float* __restrict__ bias,
    float* __restrict__ out)
{
  __shared__ unsigned short la[2][128 * 32];
  __shared__ unsigned short lb[2][64 * 32];
  const int tid = threadIdx.x;
  const int lane = tid & 63;
  const int wid = tid >> 6;
  const int l15 = lane & 15, lg = lane >> 4;
  const int wm = (wid & 1) * 64, wn = (wid >> 1) * 32;
  const int bm = blockIdx.x, bn = blockIdx.y;

  const int srow = lane >> 2;
  const int sko  = (lane & 3) * 8;

  auto STAGE = [&](int buf, int kt) {        // 3 gloads per wave
#pragma unroll
    for (int s = 0; s < 2; ++s) {
      const int seg = wid * 2 + s;
      gload16(&A[(bm * 128 + seg * 16 + srow) * CC + kt * 32 + sko], &la[buf][seg * 512]);
    }
    gload16(&W[(bn * 64 + wid * 16 + srow) * CC + kt * 32 + sko], &lb[buf][wid * 512]);
  };

  f32x4 acc[4][2];
#pragma unroll
  for (int i = 0; i < 4; ++i)
#pragma unroll
    for (int j = 0; j < 2; ++j) acc[i][j] = f32x4{0.f, 0.f, 0.f, 0.f};

  auto COMPUTE = [&](int buf) {
    bf16x8 af[4], bf[2];
#pragma unroll
    for (int mi = 0; mi < 4; ++mi)
      af[mi] = __builtin_bit_cast(bf16x8,
        *reinterpret_cast<const us8*>(&la[buf][(wm + mi * 16 + l15) * 32 + lg * 8]));
#pragma unroll
    for (int ni = 0; ni < 2; ++ni)
      bf[ni] = __builtin_bit_cast(bf16x8,
        *reinterpret_cast<const us8*>(&lb[buf][(wn + ni * 16 + l15) * 32 + lg * 8]));
#pragma unroll
    for (int mi = 0; mi < 4; ++mi)
#pragma unroll
      for (int ni = 0; ni < 2; ++ni)
        acc[mi][ni] = __builtin_amdgcn_mfma_f32_16x16x32_bf16(af[mi], bf[ni], acc[mi][ni], 0, 0, 0);
  };

  STAGE(0, 0);
  STAGE(1, 1);
  int cur = 0;
  for (int kt = 0; kt < CC / 32 - 1; ++kt) {
    asm volatile("s_waitcnt vmcnt(3)" ::: "memory");
    __builtin_amdgcn_s_barrier();
    COMPUTE(cur);
    __builtin_amdgcn_s_barrier();
    if (kt < CC / 32 - 2) STAGE(cur, kt + 2);
    cur ^= 1;
  }
  asm volatile("s_waitcnt vmcnt(0)" ::: "memory");
  __builtin_amdgcn_s_barrier();
  COMPUTE(cur);

#pragma unroll
  for (int ni = 0; ni < 2; ++ni) {
    const int n = bn * 64 + wn + ni * 16 + l15;
    const float bvl = bias[n];
#pragma unroll
    for (int mi = 0; mi < 4; ++mi)
#pragma unroll
      for (int r = 0; r < 4; ++r) {
        const int m = bm * 128 + wm + mi * 16 + lg * 4 + r;
        out[m * CC + n] = acc[mi][ni][r] + bvl;
      }
  }
}

// ---------------- flash attention v4 ----------------
// 1 wave/block, XCD-swizzled. Per kt: QK(B)->SM(B)->QK(A)->SM(A)->one lgkm->PV(B)+PV(A).
// Q pre-scaled (exp2 domain). PV operands SWAPPED: o^T layout col=q=l15 ==
// softmax-state lane -> in-lane rescale/normalize, zero cross-lane remap.
__global__ __launch_bounds__(64) void k_attn(
    const unsigned short* __restrict__ Q,   // [BH][T][D] bf16 (pre-scaled)
    const unsigned short* __restrict__ K,   // [BH][T][D] bf16
    const unsigned short* __restrict__ VT,  // [BH][D][T] bf16
    unsigned short* __restrict__ Y)         // [B][T][C] bf16
{
  __shared__ unsigned short pl[2][2][16][80];  // [set][qi][q-row][key], padded rows
  const int lane = threadIdx.x;
  const int l15 = lane & 15, lg = lane >> 4;
  // bijective XCD swizzle (1024 blocks % 8 == 0): each XCD gets 4 complete heads.
  const int wg = blockIdx.x + 32 * blockIdx.y;
  const int swz = (wg & 7) * 128 + (wg >> 3);
  const int p = swz & 31;                  // q-pair index 0..31
  const int bh = swz >> 5;                 // head 0..31
  const int b = bh >> 4, h = bh & 15;
  const int qb0A = p * 32;                 // low q-block
  const int qb0B = (63 - p) * 32;          // high q-block
  const int nktA = (qb0A + 95) >> 6;
  const int nktB = (qb0B + 95) >> 6;       // nktA + nktB == 33 for all p

  const unsigned short* Qh = Q + bh * TT * DD;
  const unsigned short* Kh = K + bh * TT * DD;
  const unsigned short* Vh = VT + bh * DD * TT;

  auto ldq = [&](bf16x8 (&qf)[2][2], int qb0) {
#pragma unroll
    for (int qi = 0; qi < 2; ++qi)
#pragma unroll
      for (int kk = 0; kk < 2; ++kk)
        qf[qi][kk] = __builtin_bit_cast(bf16x8,
          *reinterpret_cast<const us8*>(&Qh[(qb0 + qi * 16 + l15) * DD + kk * 32 + lg * 8]));
  };

  bf16x8 qfA[2][2], qfB[2][2];
  ldq(qfA, qb0A); ldq(qfB, qb0B);

  f32x4 oA[2][4], oB[2][4];            // o^T: lane(l15,lg) reg r = o[q=l15][d=dc*16+lg*4+r]
  float mrA[2], lrA[2], mrB[2], lrB[2];
#pragma unroll
  for (int qi = 0; qi < 2; ++qi) {
    mrA[qi] = -INFINITY; lrA[qi] = 0.f;
    mrB[qi] = -INFINITY; lrB[qi] = 0.f;
#pragma unroll
    for (int dc = 0; dc < 4; ++dc) {
      oA[qi][dc] = f32x4{0.f, 0.f, 0.f, 0.f};
      oB[qi][dc] = f32x4{0.f, 0.f, 0.f, 0.f};
    }
  }

  for (int kt = 0; kt < nktB; ++kt) {
    const int kbase = kt * 64;
    // K/V fragment loads (shared by both sets)
    bf16x8 kf[4][2], vf[2][4];
#pragma unroll
    for (int f = 0; f < 4; ++f)
#pragma unroll
      for (int kk = 0; kk < 2; ++kk)
        kf[f][kk] = __builtin_bit_cast(bf16x8,
          *reinterpret_cast<const us8*>(&Kh[(kbase + f * 16 + l15) * DD + kk * 32 + lg * 8]));
#pragma unroll
    for (int kk = 0; kk < 2; ++kk)
#pragma unroll
      for (int dc = 0; dc < 4; ++dc)
        vf[kk][dc] = __builtin_bit_cast(bf16x8,
          *reinterpret_cast<const us8*>(&Vh[(dc * 16 + l15) * TT + kbase + kk * 32 + lg * 8]));

    const bool doA = (kt < nktA);

    auto qk_sm = [&](const bf16x8 (&qf)[2][2], const int qb0, float (&mr)[2],
                     float (&lr)[2], f32x4 (&o)[2][4],
                     unsigned short (&plS)[2][16][80]) {
      // S^T = K Q^T : C[row=key=lg*4+r][col=q=l15]; Q pre-scaled -> exp2 domain
      f32x4 s[2][4];
#pragma unroll
      for (int qi = 0; qi < 2; ++qi)
#pragma unroll
        for (int f = 0; f < 4; ++f) {
          f32x4 t0 = __builtin_amdgcn_mfma_f32_16x16x32_bf16(kf[f][0], qf[qi][0],
                                                             f32x4{0.f,0.f,0.f,0.f}, 0, 0, 0);
          s[qi][f] = __builtin_amdgcn_mfma_f32_16x16x32_bf16(kf[f][1], qf[qi][1], t0, 0, 0, 0);
        }
      const bool needMask = (kbase + 63 > qb0);  // wave-uniform
#pragma unroll
      for (int qi = 0; qi < 2; ++qi) {
        const int qg = qb0 + qi * 16 + l15;
        float mt = -INFINITY;
#pragma unroll
        for (int f = 0; f < 4; ++f)
#pragma unroll
          for (int r = 0; r < 4; ++r) {
            float v = s[qi][f][r];
            if (needMask) v = (kbase + f * 16 + lg * 4 + r <= qg) ? v : -INFINITY;
            s[qi][f][r] = v;
            mt = fmaxf(mt, v);
          }
        mt = fmaxf(mt, __shfl_xor(mt, 16));
        mt = fmaxf(mt, __shfl_xor(mt, 32));
        const float mn = fmaxf(mr[qi], mt);
        const float al = FEXP2(mr[qi] - mn);   // first tile: exp2(-inf)=0
        mr[qi] = mn;
        float rs = 0.f;
#pragma unroll
        for (int f = 0; f < 4; ++f) {
          const float p0 = FEXP2(s[qi][f][0] - mn), p1 = FEXP2(s[qi][f][1] - mn);
          const float p2 = FEXP2(s[qi][f][2] - mn), p3 = FEXP2(s[qi][f][3] - mn);
          rs += (p0 + p1) + (p2 + p3);
          bf16x4 pk;
          pk[0] = (__bf16)p0; pk[1] = (__bf16)p1; pk[2] = (__bf16)p2; pk[3] = (__bf16)p3;
          *reinterpret_cast<bf16x4*>(&plS[qi][l15][f * 16 + lg * 4]) = pk;
        }
        rs += __shfl_xor(rs, 16);
        rs += __shfl_xor(rs, 32);
        lr[qi] = lr[qi] * al + rs;
        // in-lane rescale: o^T col=q=l15 == this lane's softmax row
#pragma unroll
        for (int dc = 0; dc < 4; ++dc)
#pragma unroll
          for (int r = 0; r < 4; ++r) o[qi][dc][r] *= al;
      }
    };

    qk_sm(qfB, qb0B, mrB, lrB, oB, pl[0]);
    if (doA) qk_sm(qfA, qb0A, mrA, lrA, oA, pl[1]);

    asm volatile("s_waitcnt lgkmcnt(0)" ::: "memory");  // all P stores visible
    __builtin_amdgcn_sched_barrier(0);

    auto pv = [&](f32x4 (&o)[2][4], unsigned short (&plS)[2][16][80]) {
#pragma unroll
      for (int qi = 0; qi < 2; ++qi) {
        const bf16x8 pa0 = __builtin_bit_cast(bf16x8,
          *reinterpret_cast<const us8*>(&plS[qi][l15][lg * 8]));
        const bf16x8 pa1 = __builtin_bit_cast(bf16x8,
          *reinterpret_cast<const us8*>(&plS[qi][l15][32 + lg * 8]));
#pragma unroll
        for (int dc = 0; dc < 4; ++dc) {
          // SWAPPED: mfma(V, P) -> D[col=q=l15][row=d] = o^T
          o[qi][dc] = __builtin_amdgcn_mfma_f32_16x16x32_bf16(vf[0][dc], pa0, o[qi][dc], 0, 0, 0);
          o[qi][dc] = __builtin_amdgcn_mfma_f32_16x16x32_bf16(vf[1][dc], pa1, o[qi][dc], 0, 0, 0);
        }
      }
    };
    pv(oB, pl[0]);
    if (doA) pv(oA, pl[1]);
  }

  // epilogue (o^T): lane(l15,lg) holds o[q=l15][d=dc*16+lg*4+r]; m/l in-lane.
  auto epi = [&](int qb0, f32x4 (&o)[2][4], float (&lr)[2]) {
#pragma unroll
    for (int qi = 0; qi < 2; ++qi) {
      const float linv = 1.f / lr[qi];
      const int t = qb0 + qi * 16 + l15;
#pragma unroll
      for (int dc = 0; dc < 4; ++dc) {
        bf16x4 pk;
#pragma unroll
        for (int r = 0; r < 4; ++r)
          pk[r] = __builtin_bit_cast(__bf16, f2b(o[qi][dc][r] * linv));
        *reinterpret_cast<bf16x4*>(
            &Y[(b * TT + t) * CC + h * DD + dc * 16 + lg * 4]) = pk;
      }
    }
  };
  epi(qb0B, oB, lrB);
  epi(qb0A, oA, lrA);
}

extern "C" void kernel_launch(void* const* d_in, const int* in_sizes, int n_in,
                              void* d_out, int out_size, void* d_ws, size_t ws_size,
                              hipStream_t stream) {
  const float* x  = (const float*)d_in[0];
  const float* Wq = (const float*)d_in[1];
  const float* bq = (const float*)d_in[2];
  const float* Wk = (const float*)d_in[3];
  const float* bk = (const float*)d_in[4];
  const float* Wv = (const float*)d_in[5];
  const float* bv = (const float*)d_in[6];
  const float* Wo = (const float*)d_in[7];
  const float* bo = (const float*)d_in[8];
  float* out = (float*)d_out;

  unsigned short* ws  = (unsigned short*)d_ws;
  unsigned short* xb  = ws;               // x bf16       [4096][1024]
  unsigned short* wqb = xb  + 4194304;    // Wq bf16
  unsigned short* wkb = wqb + 1048576;
  unsigned short* wvb = wkb + 1048576;
  unsigned short* wob = wvb + 1048576;
  unsigned short* qb  = wob + 1048576;    // Q  [BH][T][D] (pre-scaled)
  unsigned short* kb  = qb  + 4194304;    // K  [BH][T][D]
  unsigned short* vt  = kb  + 4194304;    // V^T [BH][D][T]
  unsigned short* yb  = xb;               // attn out [B][T][C] — aliases xb (dead after QKV GEMM)

  k_cvt_all<<<8192, 256, 0, stream>>>(x, Wq, Wk, Wv, Wo, ws);

  k_gemm_qkv<<<dim3(32, 24), 256, 0, stream>>>(xb, wqb, wkb, wvb, bq, bk, bv, qb, kb, vt);

  k_attn<<<dim3(32, 32), 64, 0, stream>>>(qb, kb, vt, yb);

  k_gemm_o<<<dim3(32, 16), 256, 0, stream>>>(yb, wob, bo, out);
}

// Round 15
// 206.778 us; speedup vs baseline: 1.0169x; 1.0169x over previous
//
#include <hip/hip_runtime.h>
#include <hip/hip_bf16.h>

// Problem: B=2, T=2048, C=1024, H=16, D=64 causal self-attention fwd.
// All inputs fp32; output fp32. Compute in bf16 MFMA (threshold = 2% of max|ref|).

namespace {

constexpr int TT = 2048;
constexpr int CC = 1024;
constexpr int HH = 16;
constexpr int DD = 64;

using bf16x8 = __attribute__((ext_vector_type(8))) __bf16;
using bf16x4 = __attribute__((ext_vector_type(4))) __bf16;
using f32x4  = __attribute__((ext_vector_type(4))) float;
using f32x16 = __attribute__((ext_vector_type(16))) float;
using us8    = __attribute__((ext_vector_type(8))) unsigned short;

__device__ __forceinline__ unsigned short f2b(float f) {
  unsigned u = __float_as_uint(f);
  u += 0x7fffu + ((u >> 16) & 1u);   // RNE
  return (unsigned short)(u >> 16);
}

// async global->LDS, 16B per lane; LDS dest is wave-uniform base + lane*16
__device__ __forceinline__ void gload16(const void* g, void* l) {
  __builtin_amdgcn_global_load_lds(
      (const __attribute__((address_space(1))) void*)g,
      (__attribute__((address_space(3))) void*)l, 16, 0, 0);
}

#if __has_builtin(__builtin_amdgcn_exp2f)
#define FEXP2 __builtin_amdgcn_exp2f
#else
#define FEXP2 exp2f
#endif

// 1/sqrt(64) * log2(e): folded into the Q projection epilogue -> attn softmax
// runs directly in the exp2 domain with NO per-score scaling.
#define SCALE2 0.18033688011112042f

} // namespace

// ---------------- fp32 -> bf16 conversion: all 5 tensors in ONE launch ----------------
__global__ void k_cvt_all(const float* __restrict__ x,
                          const float* __restrict__ wq, const float* __restrict__ wk,
                          const float* __restrict__ wv, const float* __restrict__ wo,
                          unsigned short* __restrict__ dst) {
  const int i = blockIdx.x * 256 + threadIdx.x;   // 0 .. 2097151 float4s
  const float* src; int off;
  if (i < 1048576)      { src = x;  off = i; }
  else if (i < 1310720) { src = wq; off = i - 1048576; }
  else if (i < 1572864) { src = wk; off = i - 1310720; }
  else if (i < 1835008) { src = wv; off = i - 1572864; }
  else                  { src = wo; off = i - 1835008; }
  float4 v = reinterpret_cast<const float4*>(src)[off];
  ushort4 o;
  o.x = f2b(v.x); o.y = f2b(v.y); o.z = f2b(v.z); o.w = f2b(v.w);
  reinterpret_cast<ushort4*>(dst)[i] = o;
}

// ---------------- fused QKV GEMM, 2-deep counted-vmcnt pipeline (R10 verified) ----------------
// Q output is PRE-SCALED by SCALE2 (softmax exp2-domain fold).
__global__ __launch_bounds__(256, 3) void k_gemm_qkv(
    const unsigned short* __restrict__ A,    // x bf16 [4096][1024]
    const unsigned short* __restrict__ Wq,
    const unsigned short* __restrict__ Wk,
    const unsigned short* __restrict__ Wv,
    const float* __restrict__ bq,
    const float* __restrict__ bk,
    const float* __restrict__ bv,
    unsigned short* __restrict__ qd,         // [BH][T][D]  (pre-scaled)
    unsigned short* __restrict__ kd,         // [BH][T][D]
    unsigned short* __restrict__ vd)         // [BH][D][T]
{
  __shared__ unsigned short la[2][128 * 32];   // 2 x 8 KB
  __shared__ unsigned short lb[2][128 * 32];
  const int tid = threadIdx.x;
  const int lane = tid & 63;
  const int wid = tid >> 6;
  const int l15 = lane & 15, lg = lane >> 4;
  const int wm = (wid & 1) * 64, wn = (wid >> 1) * 64;
  const int bm = blockIdx.x;
  const int wsel = blockIdx.y >> 3;          // 0=Q 1=K 2=V
  const int bnl = blockIdx.y & 7;

  const unsigned short* W = (wsel == 0) ? Wq : (wsel == 1) ? Wk : Wv;
  const float* bias = (wsel == 0) ? bq : (wsel == 1) ? bk : bv;

  const int srow = lane >> 2;                // 0..15 within segment
  const int sko  = (lane & 3) * 8;           // k-chunk 0/8/16/24

  auto STAGE = [&](int buf, int kt) {        // 4 gloads per wave
#pragma unroll
    for (int s = 0; s < 2; ++s) {
      const int seg = wid * 2 + s;           // 0..7 (16 rows each)
      const int row = seg * 16 + srow;
      gload16(&A[(bm * 128 + row) * CC + kt * 32 + sko], &la[buf][seg * 512]);
      gload16(&W[(bnl * 128 + row) * CC + kt * 32 + sko], &lb[buf][seg * 512]);
    }
  };

  f32x4 acc[4][4];
#pragma unroll
  for (int i = 0; i < 4; ++i)
#pragma unroll
    for (int j = 0; j < 4; ++j) acc[i][j] = f32x4{0.f, 0.f, 0.f, 0.f};

  auto COMPUTE = [&](int buf) {
    bf16x8 af[4], bf[4];
#pragma unroll
    for (int mi = 0; mi < 4; ++mi)
      af[mi] = __builtin_bit_cast(bf16x8,
        *reinterpret_cast<const us8*>(&la[buf][(wm + mi * 16 + l15) * 32 + lg * 8]));
#pragma unroll
    for (int ni = 0; ni < 4; ++ni)
      bf[ni] = __builtin_bit_cast(bf16x8,
        *reinterpret_cast<const us8*>(&lb[buf][(wn + ni * 16 + l15) * 32 + lg * 8]));
#pragma unroll
    for (int mi = 0; mi < 4; ++mi)
#pragma unroll
      for (int ni = 0; ni < 4; ++ni)
        acc[mi][ni] = __builtin_amdgcn_mfma_f32_16x16x32_bf16(af[mi], bf[ni], acc[mi][ni], 0, 0, 0);
  };

  STAGE(0, 0);
  STAGE(1, 1);
  int cur = 0;
  for (int kt = 0; kt < CC / 32 - 1; ++kt) {
    asm volatile("s_waitcnt vmcnt(4)" ::: "memory");   // tile kt landed; kt+1 flying
    __builtin_amdgcn_s_barrier();
    COMPUTE(cur);
    __builtin_amdgcn_s_barrier();
    if (kt < CC / 32 - 2) STAGE(cur, kt + 2);
    cur ^= 1;
  }
  asm volatile("s_waitcnt vmcnt(0)" ::: "memory");      // peeled last step: full drain
  __builtin_amdgcn_s_barrier();
  COMPUTE(cur);

  // epilogue: C/D col = lane&15, row = (lane>>4)*4 + r
#pragma unroll
  for (int ni = 0; ni < 4; ++ni) {
    const int nl = bnl * 128 + wn + ni * 16 + l15;   // 0..1023
    const float bvl = bias[nl];
    const int hh = nl >> 6, d = nl & (DD - 1);
#pragma unroll
    for (int mi = 0; mi < 4; ++mi) {
#pragma unroll
      for (int r = 0; r < 4; ++r) {
        const int m = bm * 128 + wm + mi * 16 + lg * 4 + r;
        float val = acc[mi][ni][r] + bvl;
        if (wsel == 0) val *= SCALE2;                  // pre-scale Q
        const unsigned short bb = f2b(val);
        const int b = m >> 11, t = m & (TT - 1);
        if (wsel == 0)
          qd[((b * HH + hh) * TT + t) * DD + d] = bb;
        else if (wsel == 1)
          kd[((b * HH + hh) * TT + t) * DD + d] = bb;
        else
          vd[((b * HH + hh) * DD + d) * TT + t] = bb;
      }
    }
  }
}

// ---------------- output projection GEMM, 2-deep counted-vmcnt (R10 verified) ----------------
__global__ __launch_bounds__(256, 2) void k_gemm_o(
    const unsigned short* __restrict__ A,    // y bf16 [4096][1024]
    const unsigned short* __restrict__ W,    // Wo bf16 [1024][1024]
    const float* __restrict__ bias,
    float* __restrict__ out)
{
  __shared__ unsigned short la[2][128 * 32];
  __shared__ unsigned short lb[2][64 * 32];
  const int tid = threadIdx.x;
  const int lane = tid & 63;
  const int wid = tid >> 6;
  const int l15 = lane & 15, lg = lane >> 4;
  const int wm = (wid & 1) * 64, wn = (wid >> 1) * 32;
  const int bm = blockIdx.x, bn = blockIdx.y;

  const int srow = lane >> 2;
  const int sko  = (lane & 3) * 8;

  auto STAGE = [&](int buf, int kt) {        // 3 gloads per wave
#pragma unroll
    for (int s = 0; s < 2; ++s) {
      const int seg = wid * 2 + s;
      gload16(&A[(bm * 128 + seg * 16 + srow) * CC + kt * 32 + sko], &la[buf][seg * 512]);
    }
    gload16(&W[(bn * 64 + wid * 16 + srow) * CC + kt * 32 + sko], &lb[buf][wid * 512]);
  };

  f32x4 acc[4][2];
#pragma unroll
  for (int i = 0; i < 4; ++i)
#pragma unroll
    for (int j = 0; j < 2; ++j) acc[i][j] = f32x4{0.f, 0.f, 0.f, 0.f};

  auto COMPUTE = [&](int buf) {
    bf16x8 af[4], bf[2];
#pragma unroll
    for (int mi = 0; mi < 4; ++mi)
      af[mi] = __builtin_bit_cast(bf16x8,
        *reinterpret_cast<const us8*>(&la[buf][(wm + mi * 16 + l15) * 32 + lg * 8]));
#pragma unroll
    for (int ni = 0; ni < 2; ++ni)
      bf[ni] = __builtin_bit_cast(bf16x8,
        *reinterpret_cast<const us8*>(&lb[buf][(wn + ni * 16 + l15) * 32 + lg * 8]));
#pragma unroll
    for (int mi = 0; mi < 4; ++mi)
#pragma unroll
      for (int ni = 0; ni < 2; ++ni)
        acc[mi][ni] = __builtin_amdgcn_mfma_f32_16x16x32_bf16(af[mi], bf[ni], acc[mi][ni], 0, 0, 0);
  };

  STAGE(0, 0);
  STAGE(1, 1);
  int cur = 0;
  for (int kt = 0; kt < CC / 32 - 1; ++kt) {
    asm volatile("s_waitcnt vmcnt(3)" ::: "memory");
    __builtin_amdgcn_s_barrier();
    COMPUTE(cur);
    __builtin_amdgcn_s_barrier();
    if (kt < CC / 32 - 2) STAGE(cur, kt + 2);
    cur ^= 1;
  }
  asm volatile("s_waitcnt vmcnt(0)" ::: "memory");
  __builtin_amdgcn_s_barrier();
  COMPUTE(cur);

#pragma unroll
  for (int ni = 0; ni < 2; ++ni) {
    const int n = bn * 64 + wn + ni * 16 + l15;
    const float bvl = bias[n];
#pragma unroll
    for (int mi = 0; mi < 4; ++mi)
#pragma unroll
      for (int r = 0; r < 4; ++r) {
        const int m = bm * 128 + wm + mi * 16 + lg * 4 + r;
        out[m * CC + n] = acc[mi][ni][r] + bvl;
      }
  }
}

// ---------------- flash attention v5: 32x32x16 MFMA ----------------
// 1 wave/block, XCD-swizzled, q-pair (p, 63-p). Swapped QK (mfma(K,Q)) on the
// 32x32 shape: each query's 64-key row lives on 2 lanes -> softmax reduce =
// in-lane chains + ONE shfl_xor(32) each for max and sum (8 -> 2 DS-shfl/set).
// Swapped PV (mfma(V,P)) keeps o^T col=q=lane&31 -> in-lane m/l/alpha.
// 32x32 C/D layout (m74/m101): col=lane&31, row=(reg&3)+8*(reg>>2)+4*(lane>>5).
__global__ __launch_bounds__(64) void k_attn(
    const unsigned short* __restrict__ Q,   // [BH][T][D] bf16 (pre-scaled)
    const unsigned short* __restrict__ K,   // [BH][T][D] bf16
    const unsigned short* __restrict__ VT,  // [BH][D][T] bf16
    unsigned short* __restrict__ Y)         // [B][T][C] bf16
{
  __shared__ unsigned short pl[2][32][68];  // [set][q][key], stride 68 ush = 34 banks
  const int lane = threadIdx.x;
  const int l31 = lane & 31;
  const int hi = lane >> 5;                 // 0/1
  const int klane = hi * 4;
  // bijective XCD swizzle (1024 blocks % 8 == 0): each XCD gets 4 complete heads.
  const int wg = blockIdx.x + 32 * blockIdx.y;
  const int swz = (wg & 7) * 128 + (wg >> 3);
  const int p = swz & 31;
  const int bh = swz >> 5;
  const int b = bh >> 4, h = bh & 15;
  const int qb0A = p * 32;
  const int qb0B = (63 - p) * 32;
  const int nktA = (qb0A + 95) >> 6;
  const int nktB = (qb0B + 95) >> 6;        // nktA + nktB == 33

  const unsigned short* Qh = Q + bh * TT * DD;
  const unsigned short* Kh = K + bh * TT * DD;
  const unsigned short* Vh = VT + bh * DD * TT;

  // Q frags (B-operand): col=q=l31, k=d = dk*16 + hi*8 + j
  bf16x8 qfA[4], qfB[4];
#pragma unroll
  for (int dk = 0; dk < 4; ++dk) {
    qfA[dk] = __builtin_bit_cast(bf16x8,
      *reinterpret_cast<const us8*>(&Qh[(qb0A + l31) * DD + dk * 16 + hi * 8]));
    qfB[dk] = __builtin_bit_cast(bf16x8,
      *reinterpret_cast<const us8*>(&Qh[(qb0B + l31) * DD + dk * 16 + hi * 8]));
  }

  // o^T accumulators: o[dc][reg]: d = dc*32 + (reg&3)+8*(reg>>2)+klane, q = l31
  f32x16 oA0, oA1, oB0, oB1;
#pragma unroll
  for (int r = 0; r < 16; ++r) { oA0[r] = 0.f; oA1[r] = 0.f; oB0[r] = 0.f; oB1[r] = 0.f; }
  float mrA = -INFINITY, lrA = 0.f, mrB = -INFINITY, lrB = 0.f;

  // K frags (A-operand): row=key = kb*32 + l31, k=d
  auto ldk = [&](bf16x8 (&kf)[2][4], int kb_base) {
#pragma unroll
    for (int kb = 0; kb < 2; ++kb)
#pragma unroll
      for (int dk = 0; dk < 4; ++dk)
        kf[kb][dk] = __builtin_bit_cast(bf16x8,
          *reinterpret_cast<const us8*>(&Kh[(kb_base + kb * 32 + l31) * DD + dk * 16 + hi * 8]));
  };
  // V frags (A-operand for PV): row=d = dc*32 + l31, k=key = kc*16 + hi*8 + j
  auto ldv = [&](bf16x8 (&vf)[2][4], int kb_base) {
#pragma unroll
    for (int dc = 0; dc < 2; ++dc)
#pragma unroll
      for (int kc = 0; kc < 4; ++kc)
        vf[dc][kc] = __builtin_bit_cast(bf16x8,
          *reinterpret_cast<const us8*>(&Vh[(dc * 32 + l31) * TT + kb_base + kc * 16 + hi * 8]));
  };

  auto qk_sm = [&](const bf16x8 (&kf)[2][4], const bf16x8 (&qf)[4], const int qb0,
                   float& mr, float& lr, f32x16& o0, f32x16& o1,
                   unsigned short (&plS)[32][68], const int kbase) {
    f32x16 s0, s1;
#pragma unroll
    for (int r = 0; r < 16; ++r) { s0[r] = 0.f; s1[r] = 0.f; }
#pragma unroll
    for (int dk = 0; dk < 4; ++dk) {
      s0 = __builtin_amdgcn_mfma_f32_32x32x16_bf16(kf[0][dk], qf[dk], s0, 0, 0, 0);
      s1 = __builtin_amdgcn_mfma_f32_32x32x16_bf16(kf[1][dk], qf[dk], s1, 0, 0, 0);
    }
    const int qg = qb0 + l31;
    if (kbase + 63 > qb0) {                 // wave-uniform causal mask
#pragma unroll
      for (int r = 0; r < 16; ++r) {
        const int kc0 = kbase + (r & 3) + 8 * (r >> 2) + klane;
        s0[r] = (kc0 <= qg)      ? s0[r] : -INFINITY;
        s1[r] = (kc0 + 32 <= qg) ? s1[r] : -INFINITY;
      }
    }
    // row max: two parallel in-lane chains + one cross-half shfl
    float ma = s0[0], mb = s1[0];
#pragma unroll
    for (int r = 1; r < 16; ++r) { ma = fmaxf(ma, s0[r]); mb = fmaxf(mb, s1[r]); }
    float mt = fmaxf(ma, mb);
    mt = fmaxf(mt, __shfl_xor(mt, 32));
    const float mn = fmaxf(mr, mt);
    const float al = FEXP2(mr - mn);        // first tile: exp2(-inf)=0
    mr = mn;
    // exp + pack P (bf16x4 per 4 consecutive keys) + row sum
    float rs0 = 0.f, rs1 = 0.f;
#pragma unroll
    for (int g = 0; g < 4; ++g) {
      const float a0 = FEXP2(s0[g * 4 + 0] - mn), a1 = FEXP2(s0[g * 4 + 1] - mn);
      const float a2 = FEXP2(s0[g * 4 + 2] - mn), a3 = FEXP2(s0[g * 4 + 3] - mn);
      rs0 += (a0 + a1) + (a2 + a3);
      bf16x4 pk0;
      pk0[0] = (__bf16)a0; pk0[1] = (__bf16)a1; pk0[2] = (__bf16)a2; pk0[3] = (__bf16)a3;
      *reinterpret_cast<bf16x4*>(&plS[l31][g * 8 + klane]) = pk0;
      const float b0 = FEXP2(s1[g * 4 + 0] - mn), b1 = FEXP2(s1[g * 4 + 1] - mn);
      const float b2 = FEXP2(s1[g * 4 + 2] - mn), b3 = FEXP2(s1[g * 4 + 3] - mn);
      rs1 += (b0 + b1) + (b2 + b3);
      bf16x4 pk1;
      pk1[0] = (__bf16)b0; pk1[1] = (__bf16)b1; pk1[2] = (__bf16)b2; pk1[3] = (__bf16)b3;
      *reinterpret_cast<bf16x4*>(&plS[l31][32 + g * 8 + klane]) = pk1;
    }
    float rs = rs0 + rs1;
    rs += __shfl_xor(rs, 32);
    lr = lr * al + rs;
    o0 *= al;
    o1 *= al;
  };

  auto pv = [&](const bf16x8 (&vf)[2][4], f32x16& o0, f32x16& o1,
                unsigned short (&plS)[32][68]) {
#pragma unroll
    for (int kc = 0; kc < 4; ++kc) {
      const bf16x8 pa = __builtin_bit_cast(bf16x8,
        *reinterpret_cast<const us8*>(&plS[l31][kc * 16 + hi * 8]));
      o0 = __builtin_amdgcn_mfma_f32_32x32x16_bf16(vf[0][kc], pa, o0, 0, 0, 0);
      o1 = __builtin_amdgcn_mfma_f32_32x32x16_bf16(vf[1][kc], pa, o1, 0, 0, 0);
    }
  };

  // main loop, unroll-by-2 with named K-frag double buffers (prefetch under softmax)
  bf16x8 kf0[2][4], kf1[2][4];
  ldk(kf0, 0);
  for (int kt = 0; kt < nktB; kt += 2) {
    {
      const int kbase = kt * 64;
      bf16x8 vf[2][4];
      ldv(vf, kbase);                                  // consumed at PV (after softmax)
      const int nx1 = (kt + 1 < nktB) ? kt + 1 : nktB - 1;
      ldk(kf1, nx1 * 64);                              // next-K prefetch under softmax
      qk_sm(kf0, qfB, qb0B, mrB, lrB, oB0, oB1, pl[0], kbase);
      const bool doA = (kt < nktA);
      if (doA) qk_sm(kf0, qfA, qb0A, mrA, lrA, oA0, oA1, pl[1], kbase);
      asm volatile("s_waitcnt lgkmcnt(0)" ::: "memory");
      __builtin_amdgcn_sched_barrier(0);
      pv(vf, oB0, oB1, pl[0]);
      if (doA) pv(vf, oA0, oA1, pl[1]);
    }
    if (kt + 1 < nktB) {
      const int kbase = (kt + 1) * 64;
      bf16x8 vf[2][4];
      ldv(vf, kbase);
      const int nx2 = (kt + 2 < nktB) ? kt + 2 : nktB - 1;
      ldk(kf0, nx2 * 64);
      qk_sm(kf1, qfB, qb0B, mrB, lrB, oB0, oB1, pl[0], kbase);
      const bool doA = (kt + 1 < nktA);
      if (doA) qk_sm(kf1, qfA, qb0A, mrA, lrA, oA0, oA1, pl[1], kbase);
      asm volatile("s_waitcnt lgkmcnt(0)" ::: "memory");
      __builtin_amdgcn_sched_barrier(0);
      pv(vf, oB0, oB1, pl[0]);
      if (doA) pv(vf, oA0, oA1, pl[1]);
    }
  }

  // epilogue: lane holds o^T[q=l31][d = dc*32 + 8g + klane + i]; m/l in-lane
  auto epi = [&](int qb0, const f32x16& o0, const f32x16& o1, float lr) {
    const float linv = 1.f / lr;
    const int t = qb0 + l31;
    unsigned short* yrow = &Y[(b * TT + t) * CC + h * DD];
#pragma unroll
    for (int g = 0; g < 4; ++g) {
      bf16x4 w0, w1;
#pragma unroll
      for (int i = 0; i < 4; ++i) {
        w0[i] = __builtin_bit_cast(__bf16, f2b(o0[g * 4 + i] * linv));
        w1[i] = __builtin_bit_cast(__bf16, f2b(o1[g * 4 + i] * linv));
      }
      *reinterpret_cast<bf16x4*>(&yrow[g * 8 + klane]) = w0;
      *reinterpret_cast<bf16x4*>(&yrow[32 + g * 8 + klane]) = w1;
    }
  };
  epi(qb0B, oB0, oB1, lrB);
  epi(qb0A, oA0, oA1, lrA);
}

extern "C" void kernel_launch(void* const* d_in, const int* in_sizes, int n_in,
                              void* d_out, int out_size, void* d_ws, size_t ws_size,
                              hipStream_t stream) {
  const float* x  = (const float*)d_in[0];
  const float* Wq = (const float*)d_in[1];
  const float* bq = (const float*)d_in[2];
  const float* Wk = (const float*)d_in[3];
  const float* bk = (const float*)d_in[4];
  const float* Wv = (const float*)d_in[5];
  const float* bv = (const float*)d_in[6];
  const float* Wo = (const float*)d_in[7];
  const float* bo = (const float*)d_in[8];
  float* out = (float*)d_out;

  unsigned short* ws  = (unsigned short*)d_ws;
  unsigned short* xb  = ws;               // x bf16       [4096][1024]
  unsigned short* wqb = xb  + 4194304;    // Wq bf16
  unsigned short* wkb = wqb + 1048576;
  unsigned short* wvb = wkb + 1048576;
  unsigned short* wob = wvb + 1048576;
  unsigned short* qb  = wob + 1048576;    // Q  [BH][T][D] (pre-scaled)
  unsigned short* kb  = qb  + 4194304;    // K  [BH][T][D]
  unsigned short* vt  = kb  + 4194304;    // V^T [BH][D][T]
  unsigned short* yb  = xb;               // attn out [B][T][C] — aliases xb (dead after QKV GEMM)

  k_cvt_all<<<8192, 256, 0, stream>>>(x, Wq, Wk, Wv, Wo, ws);

  k_gemm_qkv<<<dim3(32, 24), 256, 0, stream>>>(xb, wqb, wkb, wvb, bq, bk, bv, qb, kb, vt);

  k_attn<<<dim3(32, 32), 64, 0, stream>>>(qb, kb, vt, yb);

  k_gemm_o<<<dim3(32, 16), 256, 0, stream>>>(yb, wob, bo, out);
}